// Round 4
// baseline (2311.531 us; speedup 1.0000x reference)
//
#include <hip/hip_runtime.h>
#include <stdint.h>

#define THREADS 256
#define N_MAX 131072
#define B_MAX 2100000

// Static device scratch (n <= 131072 nodes, totalBlocks = n+2E <= 2.1M).
__device__ int g_cnt[N_MAX];
__device__ int g_blk_off[N_MAX + 1];
__device__ int g_cursor[N_MAX];
__device__ float g_maps_diag[(size_t)N_MAX * 16];
__device__ unsigned long long g_keys[B_MAX];
__device__ int g_blk_node[B_MAX];
__device__ int g_wide;

// edge_index may be staged int32 or int64 (values < 2^31, little-endian):
// wide==1 -> element i's low word sits at int32 index 2i.
__device__ __forceinline__ int get_ei(const int* __restrict__ ei, int wide, long long idx) {
  return ei[idx << wide];
}

__global__ void detect_wide_kernel(const int* __restrict__ ei) {
  int w = 1;
  for (int i = 0; i < 8; i++)
    if (ei[2 * i + 1] != 0) w = 0;
  g_wide = w;
}

// zero cnt[n], cursor[n], maps_diag[16n] every call (statics persist)
__global__ void zero_kernel(int n) {
  int total = 18 * n;
  for (int i = blockIdx.x * blockDim.x + threadIdx.x; i < total; i += gridDim.x * blockDim.x) {
    if (i < n) g_cnt[i] = 0;
    else if (i < 2 * n) g_cursor[i - n] = 0;
    else g_maps_diag[i - 2 * n] = 0.0f;
  }
}

// 1) degree histogram over the E undirected-entry edges
__global__ void count_deg_kernel(const int* __restrict__ ei, int E, int twoE) {
  int e = blockIdx.x * blockDim.x + threadIdx.x;
  if (e >= E) return;
  int w = g_wide;
  atomicAdd(&g_cnt[get_ei(ei, w, e)], 1);
  atomicAdd(&g_cnt[get_ei(ei, w, (long long)twoE + e)], 1);
}

// 2) diag: for ALL 2E entries of edge_index[0], maps_diag[ei0[g]] += M_g^T M_g
__global__ void diag_acc_kernel(const float* __restrict__ maps, const int* __restrict__ ei, int twoE) {
  int g = blockIdx.x * blockDim.x + threadIdx.x;
  if (g >= twoE) return;
  int w = g_wide;
  const float* M = maps + (size_t)g * 16;
  float m[16];
#pragma unroll
  for (int i = 0; i < 16; i++) m[i] = M[i];
  float* D = g_maps_diag + (size_t)get_ei(ei, w, g) * 16;
#pragma unroll
  for (int a = 0; a < 4; a++)
#pragma unroll
    for (int b = 0; b < 4; b++) {
      float s = m[0 + a] * m[0 + b] + m[4 + a] * m[4 + b] + m[8 + a] * m[8 + b] + m[12 + a] * m[12 + b];
      atomicAdd(&D[a * 4 + b], s);
    }
}

// 3) exclusive scan of (cnt[u]+1); blk_off[n] = totalBlocks
__global__ void scan_kernel(int n) {
  __shared__ int partial[1024];
  int tid = threadIdx.x;
  int chunk = (n + 1023) / 1024;
  int start = tid * chunk;
  int end = min(start + chunk, n);
  int s = 0;
  for (int u = start; u < end; u++) s += g_cnt[u] + 1;
  partial[tid] = s;
  __syncthreads();
  for (int off = 1; off < 1024; off <<= 1) {
    int v = (tid >= off) ? partial[tid - off] : 0;
    __syncthreads();
    partial[tid] += v;
    __syncthreads();
  }
  int run = (tid == 0) ? 0 : partial[tid - 1];
  for (int u = start; u < end; u++) { g_blk_off[u] = run; run += g_cnt[u] + 1; }
  if (tid == 1023) g_blk_off[n] = partial[1023];
}

// key = (v << 22) | (class << 20) | e   -- class: 0=diag, 1=ij, 2=ji; e < 2^20
__global__ void place_diag_kernel(int n) {
  int u = blockIdx.x * blockDim.x + threadIdx.x;
  if (u >= n) return;
  int p = g_blk_off[u];
  g_keys[p] = ((unsigned long long)u << 22);
  g_blk_node[p] = u;
}

__global__ void fill_edges_kernel(const int* __restrict__ ei, int E, int twoE) {
  int e = blockIdx.x * blockDim.x + threadIdx.x;
  if (e >= E) return;
  int w = g_wide;
  int u = get_ei(ei, w, e);
  int v = get_ei(ei, w, (long long)twoE + e);
  int p1 = g_blk_off[u] + 1 + atomicAdd(&g_cursor[u], 1);
  g_keys[p1] = ((unsigned long long)v << 22) | (1ULL << 20) | (unsigned long long)e;
  g_blk_node[p1] = u;
  int p2 = g_blk_off[v] + 1 + atomicAdd(&g_cursor[v], 1);
  g_keys[p2] = ((unsigned long long)u << 22) | (2ULL << 20) | (unsigned long long)e;
  g_blk_node[p2] = v;
}

// 5) per-node insertion sort (unique keys -> deterministic == stable lexsort order)
__global__ void sort_kernel(int n) {
  int u = blockIdx.x * blockDim.x + threadIdx.x;
  if (u >= n) return;
  int s = g_blk_off[u];
  int epos = g_blk_off[u + 1];
  for (int i = s + 1; i < epos; i++) {
    unsigned long long k = g_keys[i];
    int j = i - 1;
    while (j >= s && g_keys[j] > k) { g_keys[j + 1] = g_keys[j]; j--; }
    g_keys[j + 1] = k;
  }
}

// 6) emit (FLOAT32 output): one thread per block; b-major interleave for equal-v runs
__global__ void emit_kernel(const float* __restrict__ maps, int E, long long T, int totalBlocks,
                            float* __restrict__ out) {
  int idx = blockIdx.x * blockDim.x + threadIdx.x;
  if (idx >= totalBlocks) return;
  unsigned long long key = g_keys[idx];
  int u = g_blk_node[idx];
  int base = g_blk_off[u];
  int cntu = g_blk_off[u + 1] - base;
  int k = idx - base;
  int v = (int)(key >> 22);
  int cls = (int)((key >> 20) & 3ULL);
  int e = (int)(key & 0xFFFFFULL);

  int k0 = k;
  while (k0 > 0 && (int)(g_keys[base + k0 - 1] >> 22) == v) k0--;
  int k1 = k;
  while (k1 + 1 < cntu && (int)(g_keys[base + k1 + 1] >> 22) == v) k1++;
  int m = k1 - k0 + 1;
  int j = k - k0;

  float val[16];
  if (cls == 0) {
    const float* D = g_maps_diag + (size_t)u * 16;
#pragma unroll
    for (int i = 0; i < 16; i++) val[i] = D[i];
  } else {
    const float* L = maps + (size_t)e * 16;
    const float* R = maps + ((size_t)E + (size_t)e) * 16;
    float l[16], r[16];
#pragma unroll
    for (int i = 0; i < 16; i++) { l[i] = L[i]; r[i] = R[i]; }
    if (cls == 1) {
#pragma unroll
      for (int a = 0; a < 4; a++)
#pragma unroll
        for (int b = 0; b < 4; b++)
          val[a * 4 + b] = -(l[0 + a] * r[0 + b] + l[4 + a] * r[4 + b] + l[8 + a] * r[8 + b] + l[12 + a] * r[12 + b]);
    } else {
#pragma unroll
      for (int a = 0; a < 4; a++)
#pragma unroll
        for (int b = 0; b < 4; b++)
          val[a * 4 + b] = -(l[0 + b] * r[0 + a] + l[4 + b] * r[4 + a] + l[8 + b] * r[8 + a] + l[12 + b] * r[12 + a]);
    }
  }

  float* orow = out;
  float* ocol = out + T;
  float* oval = out + 2 * T;
  long long blkbase = 16LL * base + 4LL * k0;
  float cf = (float)(v * 4);
#pragma unroll
  for (int a = 0; a < 4; a++) {
    long long rowbase = blkbase + (long long)a * 4 * cntu;
    float rf = (float)(u * 4 + a);
    if (m == 1) {
      float4 rv = make_float4(rf, rf, rf, rf);
      float4 cv = make_float4(cf, cf + 1.0f, cf + 2.0f, cf + 3.0f);
      float4 vv = make_float4(val[a * 4 + 0], val[a * 4 + 1], val[a * 4 + 2], val[a * 4 + 3]);
      *reinterpret_cast<float4*>(orow + rowbase) = rv;
      *reinterpret_cast<float4*>(ocol + rowbase) = cv;
      *reinterpret_cast<float4*>(oval + rowbase) = vv;
    } else {
#pragma unroll
      for (int b = 0; b < 4; b++) {
        long long pos = rowbase + (long long)b * m + j;
        orow[pos] = rf;
        ocol[pos] = cf + (float)b;
        oval[pos] = val[a * 4 + b];
      }
    }
  }
}

extern "C" void kernel_launch(void* const* d_in, const int* in_sizes, int n_in,
                              void* d_out, int out_size, void* d_ws, size_t ws_size,
                              hipStream_t stream) {
  const float* maps = (const float*)d_in[0];
  const int* ei = (const int*)d_in[1];

  long long twoE = (long long)in_sizes[1] / 2;   // edge_index is (2, 2E)
  long long E = twoE / 2;
  long long T = (long long)out_size / 3;         // [rows(T), cols(T), vals(T)], float32
  long long totalBlocks = T / 16;                // n + 2E
  long long n = totalBlocks - twoE;
  if (n < 1 || n > N_MAX || totalBlocks > B_MAX) return;

  int iE = (int)E, i2E = (int)twoE, iN = (int)n, iB = (int)totalBlocks;
  int gE = (iE + THREADS - 1) / THREADS;
  int g2E = (i2E + THREADS - 1) / THREADS;
  int gN = (iN + THREADS - 1) / THREADS;
  int gB = (iB + THREADS - 1) / THREADS;
  int gZ = (18 * iN + THREADS - 1) / THREADS;

  detect_wide_kernel<<<1, 1, 0, stream>>>(ei);
  zero_kernel<<<gZ, THREADS, 0, stream>>>(iN);
  count_deg_kernel<<<gE, THREADS, 0, stream>>>(ei, iE, i2E);
  diag_acc_kernel<<<g2E, THREADS, 0, stream>>>(maps, ei, i2E);
  scan_kernel<<<1, 1024, 0, stream>>>(iN);
  place_diag_kernel<<<gN, THREADS, 0, stream>>>(iN);
  fill_edges_kernel<<<gE, THREADS, 0, stream>>>(ei, iE, i2E);
  sort_kernel<<<gN, THREADS, 0, stream>>>(iN);
  emit_kernel<<<gB, THREADS, 0, stream>>>(maps, iE, T, iB, (float*)d_out);
}

// Round 5
// 1197.854 us; speedup vs baseline: 1.9297x; 1.9297x over previous
//
#include <hip/hip_runtime.h>
#include <stdint.h>

#define THREADS 256
#define N_MAX 131072
#define B_MAX 2100000
#define SORT_CAP 96
#define SORT_STRIDE 97

// Static device scratch (n <= 131072 nodes, totalBlocks = n+2E <= 2.1M).
__device__ int g_cnt[N_MAX];        // blocks per node (for blk_off)
__device__ int g_cnt2[N_MAX];       // diag contributions per node (histogram of ei[0] over 2E)
__device__ int g_blk_off[N_MAX + 1];
__device__ int g_off2[N_MAX + 1];
__device__ int g_cursor[N_MAX];
__device__ int g_cur2[N_MAX];
__device__ float g_maps_diag[(size_t)N_MAX * 16];
__device__ unsigned long long g_keys[B_MAX];
__device__ int g_blk_node[B_MAX];
__device__ int g_perm[B_MAX];       // counting-sort of g in [0,2E) by ei[0][g]
__device__ int g_wide;

// edge_index staged int32 or int64 (values < 2^31, LE): wide==1 -> low word at 2*idx.
__device__ __forceinline__ int get_ei(const int* __restrict__ ei, int wide, long long idx) {
  return ei[idx << wide];
}

__global__ void detect_wide_kernel(const int* __restrict__ ei) {
  int w = 1;
  for (int i = 0; i < 8; i++)
    if (ei[2 * i + 1] != 0) w = 0;
  g_wide = w;
}

// zero cnt, cnt2, cursor, cur2 (4n ints) every call
__global__ void zero_kernel(int n) {
  int total = 4 * n;
  for (int i = blockIdx.x * blockDim.x + threadIdx.x; i < total; i += gridDim.x * blockDim.x) {
    if (i < n) g_cnt[i] = 0;
    else if (i < 2 * n) g_cnt2[i - n] = 0;
    else if (i < 3 * n) g_cursor[i - 2 * n] = 0;
    else g_cur2[i - 3 * n] = 0;
  }
}

// 1) histograms: cnt2[ei0[g]] over all 2E; cnt[row]/cnt[col] over first E
__global__ void hist_kernel(const int* __restrict__ ei, int E, int twoE) {
  int g = blockIdx.x * blockDim.x + threadIdx.x;
  if (g >= twoE) return;
  int w = g_wide;
  int a0 = get_ei(ei, w, g);
  atomicAdd(&g_cnt2[a0], 1);
  if (g < E) {
    atomicAdd(&g_cnt[a0], 1);                              // row
    atomicAdd(&g_cnt[get_ei(ei, w, (long long)twoE + g)], 1);  // col
  }
}

// 2) exclusive scans. which=0: blk_off[u] = scan(cnt[u]+1); which=1: off2[u] = scan(cnt2[u])
__global__ void scan_kernel(int n, int which) {
  __shared__ int partial[1024];
  int tid = threadIdx.x;
  int chunk = (n + 1023) / 1024;
  int start = tid * chunk;
  int end = min(start + chunk, n);
  int add1 = (which == 0) ? 1 : 0;
  const int* src = (which == 0) ? g_cnt : g_cnt2;
  int* dst = (which == 0) ? g_blk_off : g_off2;
  int s = 0;
  for (int u = start; u < end; u++) s += src[u] + add1;
  partial[tid] = s;
  __syncthreads();
  for (int off = 1; off < 1024; off <<= 1) {
    int v = (tid >= off) ? partial[tid - off] : 0;
    __syncthreads();
    partial[tid] += v;
    __syncthreads();
  }
  int run = (tid == 0) ? 0 : partial[tid - 1];
  for (int u = start; u < end; u++) { dst[u] = run; run += src[u] + add1; }
  if (tid == 1023) dst[n] = partial[1023];
}

// 3) counting-sort scatter: perm groups g in [0,2E) by destination node ei0[g]
__global__ void scatter_perm_kernel(const int* __restrict__ ei, int twoE) {
  int g = blockIdx.x * blockDim.x + threadIdx.x;
  if (g >= twoE) return;
  int w = g_wide;
  int u = get_ei(ei, w, g);
  int p = g_off2[u] + atomicAdd(&g_cur2[u], 1);
  g_perm[p] = g;
}

// 4) gather-reduce diag: one thread per node, no atomics. M^T M is symmetric -> 10 dots.
__global__ void diag_gather_kernel(const float* __restrict__ maps, int n) {
  int u = blockIdx.x * blockDim.x + threadIdx.x;
  if (u >= n) return;
  int s = g_off2[u];
  int epos = g_off2[u + 1];
  float acc[10];
#pragma unroll
  for (int i = 0; i < 10; i++) acc[i] = 0.0f;
  for (int i = s; i < epos; i++) {
    int g = g_perm[i];
    const float4* Mv = reinterpret_cast<const float4*>(maps + (size_t)g * 16);
    float4 t0 = Mv[0], t1 = Mv[1], t2 = Mv[2], t3 = Mv[3];
    float m[16] = {t0.x, t0.y, t0.z, t0.w, t1.x, t1.y, t1.z, t1.w,
                   t2.x, t2.y, t2.z, t2.w, t3.x, t3.y, t3.z, t3.w};
    int p = 0;
#pragma unroll
    for (int a = 0; a < 4; a++)
#pragma unroll
      for (int b = a; b < 4; b++) {
        acc[p] += m[0 + a] * m[0 + b] + m[4 + a] * m[4 + b] + m[8 + a] * m[8 + b] + m[12 + a] * m[12 + b];
        p++;
      }
  }
  float d[16];
  int p = 0;
#pragma unroll
  for (int a = 0; a < 4; a++)
#pragma unroll
    for (int b = a; b < 4; b++) {
      d[a * 4 + b] = acc[p];
      d[b * 4 + a] = acc[p];
      p++;
    }
  float4* D = reinterpret_cast<float4*>(g_maps_diag + (size_t)u * 16);
#pragma unroll
  for (int i = 0; i < 4; i++) D[i] = make_float4(d[4 * i], d[4 * i + 1], d[4 * i + 2], d[4 * i + 3]);
}

// key = (v << 22) | (class << 20) | e   -- class: 0=diag, 1=ij, 2=ji; e < 2^20
__global__ void place_diag_kernel(int n) {
  int u = blockIdx.x * blockDim.x + threadIdx.x;
  if (u >= n) return;
  int p = g_blk_off[u];
  g_keys[p] = ((unsigned long long)u << 22);
  g_blk_node[p] = u;
}

__global__ void fill_edges_kernel(const int* __restrict__ ei, int E, int twoE) {
  int e = blockIdx.x * blockDim.x + threadIdx.x;
  if (e >= E) return;
  int w = g_wide;
  int u = get_ei(ei, w, e);
  int v = get_ei(ei, w, (long long)twoE + e);
  int p1 = g_blk_off[u] + 1 + atomicAdd(&g_cursor[u], 1);
  g_keys[p1] = ((unsigned long long)v << 22) | (1ULL << 20) | (unsigned long long)e;
  g_blk_node[p1] = u;
  int p2 = g_blk_off[v] + 1 + atomicAdd(&g_cursor[v], 1);
  g_keys[p2] = ((unsigned long long)u << 22) | (2ULL << 20) | (unsigned long long)e;
  g_blk_node[p2] = v;
}

// 5) per-node insertion sort, staged through LDS (one wave per 64 nodes).
// stride 97 dwords*2 => lane bank offset 2*tid mod 32: only 2-way aliasing (free).
__global__ __launch_bounds__(64) void sort_lds_kernel(int n) {
  __shared__ unsigned long long lds[64 * SORT_STRIDE];  // 49.7 KB
  int u = blockIdx.x * 64 + threadIdx.x;
  if (u >= n) return;
  int s = g_blk_off[u];
  int c = g_blk_off[u + 1] - s;
  unsigned long long* mine = &lds[threadIdx.x * SORT_STRIDE];
  if (c <= SORT_CAP) {
    for (int i = 0; i < c; i++) mine[i] = g_keys[s + i];
    for (int i = 1; i < c; i++) {
      unsigned long long k = mine[i];
      int j = i - 1;
      while (j >= 0 && mine[j] > k) { mine[j + 1] = mine[j]; j--; }
      mine[j + 1] = k;
    }
    for (int i = 0; i < c; i++) g_keys[s + i] = mine[i];
  } else {  // oversize fallback (essentially never for Poisson(~33) degrees)
    for (int i = s + 1; i < s + c; i++) {
      unsigned long long k = g_keys[i];
      int j = i - 1;
      while (j >= s && g_keys[j] > k) { g_keys[j + 1] = g_keys[j]; j--; }
      g_keys[j + 1] = k;
    }
  }
}

// 6) emit (float32 out): one thread per block; b-major interleave for equal-v runs
__global__ void emit_kernel(const float* __restrict__ maps, int E, long long T, int totalBlocks,
                            float* __restrict__ out) {
  int idx = blockIdx.x * blockDim.x + threadIdx.x;
  if (idx >= totalBlocks) return;
  unsigned long long key = g_keys[idx];
  int u = g_blk_node[idx];
  int base = g_blk_off[u];
  int cntu = g_blk_off[u + 1] - base;
  int k = idx - base;
  int v = (int)(key >> 22);
  int cls = (int)((key >> 20) & 3ULL);
  int e = (int)(key & 0xFFFFFULL);

  int k0 = k;
  while (k0 > 0 && (int)(g_keys[base + k0 - 1] >> 22) == v) k0--;
  int k1 = k;
  while (k1 + 1 < cntu && (int)(g_keys[base + k1 + 1] >> 22) == v) k1++;
  int m = k1 - k0 + 1;
  int j = k - k0;

  float val[16];
  if (cls == 0) {
    const float* D = g_maps_diag + (size_t)u * 16;
#pragma unroll
    for (int i = 0; i < 16; i++) val[i] = D[i];
  } else {
    const float* L = maps + (size_t)e * 16;
    const float* R = maps + ((size_t)E + (size_t)e) * 16;
    float l[16], r[16];
#pragma unroll
    for (int i = 0; i < 16; i++) { l[i] = L[i]; r[i] = R[i]; }
    if (cls == 1) {
#pragma unroll
      for (int a = 0; a < 4; a++)
#pragma unroll
        for (int b = 0; b < 4; b++)
          val[a * 4 + b] = -(l[0 + a] * r[0 + b] + l[4 + a] * r[4 + b] + l[8 + a] * r[8 + b] + l[12 + a] * r[12 + b]);
    } else {
#pragma unroll
      for (int a = 0; a < 4; a++)
#pragma unroll
        for (int b = 0; b < 4; b++)
          val[a * 4 + b] = -(l[0 + b] * r[0 + a] + l[4 + b] * r[4 + a] + l[8 + b] * r[8 + a] + l[12 + b] * r[12 + a]);
    }
  }

  float* orow = out;
  float* ocol = out + T;
  float* oval = out + 2 * T;
  long long blkbase = 16LL * base + 4LL * k0;
  float cf = (float)(v * 4);
#pragma unroll
  for (int a = 0; a < 4; a++) {
    long long rowbase = blkbase + (long long)a * 4 * cntu;
    float rf = (float)(u * 4 + a);
    if (m == 1) {
      *reinterpret_cast<float4*>(orow + rowbase) = make_float4(rf, rf, rf, rf);
      *reinterpret_cast<float4*>(ocol + rowbase) = make_float4(cf, cf + 1.0f, cf + 2.0f, cf + 3.0f);
      *reinterpret_cast<float4*>(oval + rowbase) =
          make_float4(val[a * 4 + 0], val[a * 4 + 1], val[a * 4 + 2], val[a * 4 + 3]);
    } else {
#pragma unroll
      for (int b = 0; b < 4; b++) {
        long long pos = rowbase + (long long)b * m + j;
        orow[pos] = rf;
        ocol[pos] = cf + (float)b;
        oval[pos] = val[a * 4 + b];
      }
    }
  }
}

extern "C" void kernel_launch(void* const* d_in, const int* in_sizes, int n_in,
                              void* d_out, int out_size, void* d_ws, size_t ws_size,
                              hipStream_t stream) {
  const float* maps = (const float*)d_in[0];
  const int* ei = (const int*)d_in[1];

  long long twoE = (long long)in_sizes[1] / 2;   // edge_index is (2, 2E)
  long long E = twoE / 2;
  long long T = (long long)out_size / 3;         // [rows(T), cols(T), vals(T)], float32
  long long totalBlocks = T / 16;                // n + 2E
  long long n = totalBlocks - twoE;
  if (n < 1 || n > N_MAX || totalBlocks > B_MAX || twoE > B_MAX) return;

  int iE = (int)E, i2E = (int)twoE, iN = (int)n, iB = (int)totalBlocks;
  int gE = (iE + THREADS - 1) / THREADS;
  int g2E = (i2E + THREADS - 1) / THREADS;
  int gN = (iN + THREADS - 1) / THREADS;
  int gB = (iB + THREADS - 1) / THREADS;
  int gZ = (4 * iN + THREADS - 1) / THREADS;
  int gS = (iN + 63) / 64;

  detect_wide_kernel<<<1, 1, 0, stream>>>(ei);
  zero_kernel<<<gZ, THREADS, 0, stream>>>(iN);
  hist_kernel<<<g2E, THREADS, 0, stream>>>(ei, iE, i2E);
  scan_kernel<<<1, 1024, 0, stream>>>(iN, 0);
  scan_kernel<<<1, 1024, 0, stream>>>(iN, 1);
  scatter_perm_kernel<<<g2E, THREADS, 0, stream>>>(ei, i2E);
  diag_gather_kernel<<<gN, THREADS, 0, stream>>>(maps, iN);
  place_diag_kernel<<<gN, THREADS, 0, stream>>>(iN);
  fill_edges_kernel<<<gE, THREADS, 0, stream>>>(ei, iE, i2E);
  sort_lds_kernel<<<gS, 64, 0, stream>>>(iN);
  emit_kernel<<<gB, THREADS, 0, stream>>>(maps, iE, T, iB, (float*)d_out);
}